// Round 3
// baseline (187.819 us; speedup 1.0000x reference)
//
#include <hip/hip_runtime.h>

#define NUM_CLASSES 80
constexpr int Bn = 8;
constexpr int Gn = 128;
constexpr int An = 131072;

constexpr int TB   = 256;        // threads per block
constexpr int APT  = 2;          // anchors per thread
constexpr int ABLK = TB * APT;   // 512 anchors per tile
constexpr int T    = 4;          // tiles per block (pipelined, no barriers)
constexpr int BBLK = ABLK * T;   // 2048 anchors per block

// out layout: cls (B,A,80) | reg (B,A,4) | states (B,A)
constexpr size_t CLS_OFF = 0;
constexpr size_t REG_OFF = (size_t)Bn * An * NUM_CLASSES;
constexpr size_t ST_OFF  = REG_OFF + (size_t)Bn * An * 4;

__global__ __launch_bounds__(TB, 2) void targets_kernel(
    const float* __restrict__ ann,      // (B,G,5) x1,y1,x2,y2,label
    const float* __restrict__ anchors,  // (A,4)
    float* __restrict__ out)
{
#pragma clang fp contract(off)
    const int tid  = threadIdx.x;
    const int lane = tid & 63;
    const int wv   = tid >> 6;          // wave id within block
    const int b    = blockIdx.y;
    const int base = blockIdx.x * BBLK; // first anchor of this block

    // stage boxes once per block
    __shared__ float4 sbox[Gn];
    __shared__ float  slabel[Gn];
    for (int i = tid; i < Gn; i += TB) {
        const float* p = ann + ((size_t)b * Gn + i) * 5;
        sbox[i] = make_float4(p[0], p[1], p[2], p[3]);
        slabel[i] = p[4];
    }
    __syncthreads();                    // the ONLY barrier in the kernel

    // prefetch tile 0 anchors
    const float* ap = anchors + (size_t)(base + tid * APT) * 4;
    float4 av0 = *reinterpret_cast<const float4*>(ap);
    float4 av1 = *reinterpret_cast<const float4*>(ap + 4);

    #pragma unroll
    for (int t = 0; t < T; ++t) {
        // prefetch next tile's anchors (in flight during the g-loop)
        float4 nx0, nx1;
        if (t + 1 < T) {
            const float* np = ap + (size_t)(t + 1) * ABLK * 4;
            nx0 = *reinterpret_cast<const float4*>(np);
            nx1 = *reinterpret_cast<const float4*>(np + 4);
        }

        const float ax1[APT] = { av0.x, av1.x };
        const float ay1[APT] = { av0.y, av1.y };
        const float ax2[APT] = { av0.z, av1.z };
        const float ay2[APT] = { av0.w, av1.w };
        float wa[APT], ha[APT], area_a[APT], best[APT];
        int besti[APT];
        #pragma unroll
        for (int j = 0; j < APT; ++j) {
            wa[j] = ax2[j] - ax1[j];
            ha[j] = ay2[j] - ay1[j];
            area_a[j] = wa[j] * ha[j];        // ref op order
            best[j] = -1.0f;                  // IoU >= 0 -> g=0 wins first
            besti[j] = 0;
        }

        #pragma unroll 4
        for (int g = 0; g < Gn; ++g) {
            const float4 bv = sbox[g];        // broadcast ds_read_b128
            const float area_b = (bv.z - bv.x) * (bv.w - bv.y);  // ref order
            #pragma unroll
            for (int j = 0; j < APT; ++j) {
                float iw = fminf(ax2[j], bv.z) - fmaxf(ax1[j], bv.x);
                iw = fmaxf(iw, 0.0f);
                float ih = fminf(ay2[j], bv.w) - fmaxf(ay1[j], bv.y);
                ih = fmaxf(ih, 0.0f);
                const float inter = iw * ih;
                float uni = (area_a[j] + area_b) - inter;  // a + b - inter
                uni = fmaxf(uni, 1e-8f);
                const float iou = inter / uni;             // IEEE div
                if (iou > best[j]) { best[j] = iou; besti[j] = g; } // first tie
            }
        }

        const int a = base + t * ABLK + tid * APT;

        // states
        float st[APT];
        #pragma unroll
        for (int j = 0; j < APT; ++j)
            st[j] = (best[j] >= 0.5f) ? 1.0f : ((best[j] < 0.4f) ? 0.0f : -1.0f);
        *reinterpret_cast<float2*>(out + ST_OFF + (size_t)b * An + a) =
            make_float2(st[0], st[1]);

        // reg targets
        #pragma unroll
        for (int j = 0; j < APT; ++j) {
            const float4 gt = sbox[besti[j]];
            float4 rv;
            rv.x = ((gt.x - ax1[j]) / wa[j]) / 0.2f;
            rv.y = ((gt.y - ay1[j]) / ha[j]) / 0.2f;
            rv.z = ((gt.z - ax2[j]) / wa[j]) / 0.2f;
            rv.w = ((gt.w - ay2[j]) / ha[j]) / 0.2f;
            *reinterpret_cast<float4*>(out + REG_OFF + ((size_t)b * An + a + j) * 4) = rv;
        }

        // cls one-hot, wave-cooperative (no barrier): this wave owns 128
        // consecutive anchors -> 2560 contiguous float4s. Labels pulled from
        // the owning lane via __shfl (ds_bpermute, wave-synchronous).
        const int lab0 = (st[0] == 1.0f) ? (int)slabel[besti[0]] : 255;
        const int lab1 = (st[1] == 1.0f) ? (int)slabel[besti[1]] : 255;
        const unsigned packed = (unsigned)lab0 | ((unsigned)lab1 << 8);

        float4* dst = reinterpret_cast<float4*>(
            out + CLS_OFF + ((size_t)b * An + base + t * ABLK + wv * 128) * NUM_CLASSES);
        #pragma unroll
        for (int i = 0; i < 40; ++i) {
            const unsigned p4  = (unsigned)(i * 64 + lane); // 0..2559
            const unsigned anc = p4 / 20u;                  // local anchor 0..127
            const unsigned c0  = (p4 - anc * 20u) * 4u;     // first class of this float4
            const int pk = __shfl((int)packed, (int)(anc >> 1), 64);
            const unsigned lab = ((unsigned)pk >> ((anc & 1u) << 3)) & 0xFFu;
            float4 v;
            v.x = (c0      == lab) ? 1.0f : 0.0f;
            v.y = (c0 + 1u == lab) ? 1.0f : 0.0f;
            v.z = (c0 + 2u == lab) ? 1.0f : 0.0f;
            v.w = (c0 + 3u == lab) ? 1.0f : 0.0f;
            dst[p4] = v;
        }

        av0 = nx0; av1 = nx1;   // rotate prefetched anchors
    }
}

extern "C" void kernel_launch(void* const* d_in, const int* in_sizes, int n_in,
                              void* d_out, int out_size, void* d_ws, size_t ws_size,
                              hipStream_t stream) {
    const float* ann     = (const float*)d_in[0];   // (8,128,5)
    const float* anchors = (const float*)d_in[1];   // (131072,4)
    float* out = (float*)d_out;

    dim3 grid(An / BBLK, Bn, 1);   // 64 x 8 = 512 blocks (2 per CU)
    dim3 block(TB, 1, 1);
    targets_kernel<<<grid, block, 0, stream>>>(ann, anchors, out);
}